// Round 1
// baseline (732.320 us; speedup 1.0000x reference)
//
#include <hip/hip_runtime.h>
#include <cstdint>
#include <cstddef>

typedef _Float16 half8 __attribute__((ext_vector_type(8)));
typedef float f32x4 __attribute__((ext_vector_type(4)));

// async global->LDS, 16B per lane; LDS dest must be wave-uniform-base + lane*16
#define GLDS16(g, l) __builtin_amdgcn_global_load_lds( \
    (__attribute__((address_space(1))) void*)(g), \
    (__attribute__((address_space(3))) void*)(l), 16, 0, 0)

// ---------------------------------------------------------------------------
// fp32 -> fp16 convert (weights)
// ---------------------------------------------------------------------------
__global__ __launch_bounds__(256) void cvt_f32_f16(const float* __restrict__ src,
                                                   _Float16* __restrict__ dst, int n) {
  int i = (blockIdx.x * 256 + threadIdx.x) * 8;
  if (i >= n) return;
  float4 a = *(const float4*)(src + i);
  float4 b = *(const float4*)(src + i + 4);
  half8 h;
  h[0] = (_Float16)a.x; h[1] = (_Float16)a.y; h[2] = (_Float16)a.z; h[3] = (_Float16)a.w;
  h[4] = (_Float16)b.x; h[5] = (_Float16)b.y; h[6] = (_Float16)b.z; h[7] = (_Float16)b.w;
  *(half8*)(dst + i) = h;
}

// ---------------------------------------------------------------------------
// QKV GEMM: C[m,n] = sum_k A32[m,k]*Bh[n,k].  A fp32 (65536x512), Bh fp16
// (1536x512, K-contiguous = B^T form), out fp16 (65536x1536).
// 128x128 tile, BK=32, 4 waves in 2x2, each wave 4x4 MFMA 16x16 tiles.
// ---------------------------------------------------------------------------
__global__ __launch_bounds__(256, 3) void qkv_gemm(const float* __restrict__ A,
                                                   const _Float16* __restrict__ Bw,
                                                   _Float16* __restrict__ Cout) {
  constexpr int K = 512, NOUT = 1536;
  __shared__ union {
    struct { _Float16 As[128][40]; _Float16 Bs[128][32]; } s;  // As padded (manual stage)
    float E[2][16][132];                                        // epilogue staging
  } u;
  const int id  = blockIdx.x;
  // XCD-aware swizzle: all 12 N-tiles of a row band land on one XCD (id%8 cohort)
  const int xcd = id & 7;
  const int jj  = id >> 3;
  const int by  = (jj / 12) * 8 + xcd;
  const int bx  = jj % 12;
  const int m_base = by * 128, n_base = bx * 128;

  const int t    = threadIdx.x;
  const int lane = t & 63;
  const int wid  = t >> 6;
  const int wm   = wid >> 1, wn = wid & 1;
  const int cl   = lane & 15, q = lane >> 4;

  f32x4 acc[4][4] = {};

  // A staging map: thread -> (row ar, 16-half chunk ah) of the 128x32 fp32 tile
  const int ar = t >> 1, ah = t & 1;
  const float* aptr = A + (size_t)(m_base + ar) * K + ah * 16;

  // B staging map (global_load_lds): 64-B rows of the 128x32 fp16 tile
  const int nr0 = t >> 2;
  const int cb0 = (t & 3) * 16;                 // byte offset within row
  const _Float16* bsrc0 = Bw + (size_t)(n_base + nr0) * K + (cb0 >> 1);
  const _Float16* bsrc1 = Bw + (size_t)(n_base + 64 + nr0) * K + (cb0 >> 1);
  char* bdst0 = (char*)u.s.Bs + t * 16;
  char* bdst1 = (char*)u.s.Bs + t * 16 + 4096;

  for (int k0 = 0; k0 < K; k0 += 32) {
    // async B tile
    GLDS16(bsrc0 + k0, bdst0);
    GLDS16(bsrc1 + k0, bdst1);
    // A tile: fp32 load -> fp16 -> LDS (padded rows, 40 halves)
    const float4* ap = (const float4*)(aptr + k0);
    float4 v0 = ap[0], v1 = ap[1], v2 = ap[2], v3 = ap[3];
    half8 h0, h1;
    h0[0] = (_Float16)v0.x; h0[1] = (_Float16)v0.y; h0[2] = (_Float16)v0.z; h0[3] = (_Float16)v0.w;
    h0[4] = (_Float16)v1.x; h0[5] = (_Float16)v1.y; h0[6] = (_Float16)v1.z; h0[7] = (_Float16)v1.w;
    h1[0] = (_Float16)v2.x; h1[1] = (_Float16)v2.y; h1[2] = (_Float16)v2.z; h1[3] = (_Float16)v2.w;
    h1[4] = (_Float16)v3.x; h1[5] = (_Float16)v3.y; h1[6] = (_Float16)v3.z; h1[7] = (_Float16)v3.w;
    *(half8*)&u.s.As[ar][ah * 16]     = h0;
    *(half8*)&u.s.As[ar][ah * 16 + 8] = h1;
    __syncthreads();   // drains vmcnt (global_load_lds) + lgkm

    half8 af[4], bf[4];
#pragma unroll
    for (int i = 0; i < 4; i++) af[i] = *(const half8*)&u.s.As[wm * 64 + i * 16 + cl][q * 8];
#pragma unroll
    for (int i = 0; i < 4; i++) bf[i] = *(const half8*)&u.s.Bs[wn * 64 + i * 16 + cl][q * 8];
#pragma unroll
    for (int mt = 0; mt < 4; mt++)
#pragma unroll
      for (int nt = 0; nt < 4; nt++)
        acc[mt][nt] = __builtin_amdgcn_mfma_f32_16x16x32_f16(af[mt], bf[nt], acc[mt][nt], 0, 0, 0);
    __syncthreads();
  }

  // epilogue: C/D layout (row=q*4+reg, col=lane&15) -> LDS -> coalesced half8 stores
  const int ebnd = t >> 7, erow = (t >> 3) & 15, ecs = t & 7;
#pragma unroll
  for (int mt = 0; mt < 4; mt++) {
#pragma unroll
    for (int nt = 0; nt < 4; nt++)
#pragma unroll
      for (int r = 0; r < 4; r++)
        u.E[wm][q * 4 + r][wn * 64 + nt * 16 + cl] = acc[mt][nt][r];
    __syncthreads();
    const float* ep = &u.E[ebnd][erow][ecs * 16];
    float4 e0 = *(const float4*)ep;
    float4 e1 = *(const float4*)(ep + 4);
    float4 e2 = *(const float4*)(ep + 8);
    float4 e3 = *(const float4*)(ep + 12);
    half8 h0, h1;
    h0[0] = (_Float16)e0.x; h0[1] = (_Float16)e0.y; h0[2] = (_Float16)e0.z; h0[3] = (_Float16)e0.w;
    h0[4] = (_Float16)e1.x; h0[5] = (_Float16)e1.y; h0[6] = (_Float16)e1.z; h0[7] = (_Float16)e1.w;
    h1[0] = (_Float16)e2.x; h1[1] = (_Float16)e2.y; h1[2] = (_Float16)e2.z; h1[3] = (_Float16)e2.w;
    h1[4] = (_Float16)e3.x; h1[5] = (_Float16)e3.y; h1[6] = (_Float16)e3.z; h1[7] = (_Float16)e3.w;
    size_t rg = (size_t)(m_base + ebnd * 64 + mt * 16 + erow);
    _Float16* dst = Cout + rg * NOUT + n_base + ecs * 16;
    *(half8*)dst = h0;
    *((half8*)dst + 1) = h1;
    __syncthreads();
  }
}

// ---------------------------------------------------------------------------
// Windowed attention: one block per (window b, head h). W=64, hd=64.
// QKV rows: token = b*64+w, cols: q=h*64+e, k=512+h*64+e, v=1024+h*64+e.
// ---------------------------------------------------------------------------
__global__ __launch_bounds__(256, 3) void attn_win(const _Float16* __restrict__ QKV,
                                                   _Float16* __restrict__ Out) {
  __shared__ _Float16 Qs[64][64];
  __shared__ _Float16 Ks[64][64];
  __shared__ _Float16 Vt[64][72];   // V transposed: Vt[e][j], padded rows (144B, 16B-aligned)
  __shared__ _Float16 Ps[64][72];   // softmax probs, padded
  __shared__ _Float16 Os[64][72];   // output staging, padded
  const int h = blockIdx.x, b = blockIdx.y;
  const int t = threadIdx.x;
  const int lane = t & 63, wid = t >> 6;
  const int cl = lane & 15, q = lane >> 4;

  // ---- stage Q,K (async, row-major) and V (manual transpose) ----
  {
    const int row0 = t >> 3;
    const int cb = (t & 7) * 16;
    const size_t rb0 = (size_t)(b * 64 + row0) * 1536;
    const size_t rb1 = (size_t)(b * 64 + 32 + row0) * 1536;
    GLDS16((const char*)(QKV + rb0 + h * 64) + cb, (char*)Qs + t * 16);
    GLDS16((const char*)(QKV + rb1 + h * 64) + cb, (char*)Qs + t * 16 + 4096);
    GLDS16((const char*)(QKV + rb0 + 512 + h * 64) + cb, (char*)Ks + t * 16);
    GLDS16((const char*)(QKV + rb1 + 512 + h * 64) + cb, (char*)Ks + t * 16 + 4096);

    const int vj = t & 63, vp = t >> 6;   // row j of V, 16-half chunk vp
    const _Float16* vsrc = QKV + (size_t)(b * 64 + vj) * 1536 + 1024 + h * 64 + vp * 16;
    half8 v0 = *(const half8*)vsrc;
    half8 v1 = *(const half8*)(vsrc + 8);
#pragma unroll
    for (int i = 0; i < 8; i++) Vt[vp * 16 + i][vj] = v0[i];
#pragma unroll
    for (int i = 0; i < 8; i++) Vt[vp * 16 + 8 + i][vj] = v1[i];
  }
  __syncthreads();

  const int m0 = wid * 16;   // wave's 16 query rows

  // ---- S = Q K^T (BT-form: both operands K-contiguous) ----
  f32x4 s[4] = {};
#pragma unroll
  for (int ks = 0; ks < 2; ks++) {
    half8 a = *(const half8*)&Qs[m0 + cl][ks * 32 + q * 8];
#pragma unroll
    for (int nt = 0; nt < 4; nt++) {
      half8 bb = *(const half8*)&Ks[nt * 16 + cl][ks * 32 + q * 8];
      s[nt] = __builtin_amdgcn_mfma_f32_16x16x32_f16(a, bb, s[nt], 0, 0, 0);
    }
  }

  // ---- softmax over 64 keys per row (row=q*4+r, keys spread over cl x nt) ----
  constexpr float SC = 0.125f * 1.44269504088896340736f;  // scale * log2(e)
#pragma unroll
  for (int r = 0; r < 4; r++) {
    float mx = fmaxf(fmaxf(s[0][r], s[1][r]), fmaxf(s[2][r], s[3][r]));
    mx = fmaxf(mx, __shfl_xor(mx, 1));
    mx = fmaxf(mx, __shfl_xor(mx, 2));
    mx = fmaxf(mx, __shfl_xor(mx, 4));
    mx = fmaxf(mx, __shfl_xor(mx, 8));
    float e[4], ssum = 0.f;
#pragma unroll
    for (int nt = 0; nt < 4; nt++) { e[nt] = exp2f((s[nt][r] - mx) * SC); ssum += e[nt]; }
    ssum += __shfl_xor(ssum, 1);
    ssum += __shfl_xor(ssum, 2);
    ssum += __shfl_xor(ssum, 4);
    ssum += __shfl_xor(ssum, 8);
    float inv = 1.f / ssum;
    const int row = m0 + q * 4 + r;
#pragma unroll
    for (int nt = 0; nt < 4; nt++) Ps[row][nt * 16 + cl] = (_Float16)(e[nt] * inv);
  }
  __syncthreads();

  // ---- O = P V  (a-frag: Ps rows; b-frag: Vt rows = V columns) ----
  f32x4 o[4] = {};
#pragma unroll
  for (int ks = 0; ks < 2; ks++) {
    half8 a = *(const half8*)&Ps[m0 + cl][ks * 32 + q * 8];
#pragma unroll
    for (int nt = 0; nt < 4; nt++) {
      half8 bb = *(const half8*)&Vt[nt * 16 + cl][ks * 32 + q * 8];
      o[nt] = __builtin_amdgcn_mfma_f32_16x16x32_f16(a, bb, o[nt], 0, 0, 0);
    }
  }
#pragma unroll
  for (int nt = 0; nt < 4; nt++)
#pragma unroll
    for (int r = 0; r < 4; r++)
      Os[m0 + q * 4 + r][nt * 16 + cl] = (_Float16)o[nt][r];
  __syncthreads();

  // ---- coalesced write-out: out[token = b*64+row][h*64 + e] ----
  {
    const int row = t >> 2, cs = t & 3;
    half8 h0 = *(const half8*)&Os[row][cs * 16];
    half8 h1 = *(const half8*)&Os[row][cs * 16 + 8];
    _Float16* dst = Out + (size_t)(b * 64 + row) * 512 + h * 64 + cs * 16;
    *(half8*)dst = h0;
    *((half8*)dst + 1) = h1;
  }
}

// ---------------------------------------------------------------------------
// Proj GEMM: out[m,n] = sum_k A[m,k]*Bw[n,k] + bias[n].  fp16 in, fp32 out.
// ---------------------------------------------------------------------------
__global__ __launch_bounds__(256, 3) void proj_gemm(const _Float16* __restrict__ A,
                                                    const _Float16* __restrict__ Bw,
                                                    const float* __restrict__ bias,
                                                    float* __restrict__ Cout) {
  constexpr int K = 512, NOUT = 512;
  __shared__ union {
    struct { _Float16 As[128][32]; _Float16 Bs[128][32]; } s;
    float E[2][16][132];
  } u;
  const int id  = blockIdx.x;
  const int xcd = id & 7;
  const int jj  = id >> 3;
  const int by  = (jj >> 2) * 8 + xcd;
  const int bx  = jj & 3;
  const int m_base = by * 128, n_base = bx * 128;

  const int t    = threadIdx.x;
  const int lane = t & 63;
  const int wid  = t >> 6;
  const int wm   = wid >> 1, wn = wid & 1;
  const int cl   = lane & 15, q = lane >> 4;

  f32x4 acc[4][4] = {};

  const int nr0 = t >> 2;
  const int cb  = (t & 3) * 16;
  const _Float16* asrc0 = A + (size_t)(m_base + nr0) * K + (cb >> 1);
  const _Float16* asrc1 = asrc0 + (size_t)64 * K;
  const _Float16* bsrc0 = Bw + (size_t)(n_base + nr0) * K + (cb >> 1);
  const _Float16* bsrc1 = bsrc0 + (size_t)64 * K;
  char* adst0 = (char*)u.s.As + t * 16;
  char* adst1 = (char*)u.s.As + t * 16 + 4096;
  char* bdst0 = (char*)u.s.Bs + t * 16;
  char* bdst1 = (char*)u.s.Bs + t * 16 + 4096;

  for (int k0 = 0; k0 < K; k0 += 32) {
    GLDS16(asrc0 + k0, adst0);
    GLDS16(asrc1 + k0, adst1);
    GLDS16(bsrc0 + k0, bdst0);
    GLDS16(bsrc1 + k0, bdst1);
    __syncthreads();
    half8 af[4], bf[4];
#pragma unroll
    for (int i = 0; i < 4; i++) af[i] = *(const half8*)&u.s.As[wm * 64 + i * 16 + cl][q * 8];
#pragma unroll
    for (int i = 0; i < 4; i++) bf[i] = *(const half8*)&u.s.Bs[wn * 64 + i * 16 + cl][q * 8];
#pragma unroll
    for (int mt = 0; mt < 4; mt++)
#pragma unroll
      for (int nt = 0; nt < 4; nt++)
        acc[mt][nt] = __builtin_amdgcn_mfma_f32_16x16x32_f16(af[mt], bf[nt], acc[mt][nt], 0, 0, 0);
    __syncthreads();
  }

  const int ebnd = t >> 7, erow = (t >> 3) & 15, ecs = t & 7;
#pragma unroll
  for (int mt = 0; mt < 4; mt++) {
#pragma unroll
    for (int nt = 0; nt < 4; nt++)
#pragma unroll
      for (int r = 0; r < 4; r++)
        u.E[wm][q * 4 + r][wn * 64 + nt * 16 + cl] = acc[mt][nt][r];
    __syncthreads();
    const float* ep = &u.E[ebnd][erow][ecs * 16];
    float4 e0 = *(const float4*)ep;
    float4 e1 = *(const float4*)(ep + 4);
    float4 e2 = *(const float4*)(ep + 8);
    float4 e3 = *(const float4*)(ep + 12);
    const int col = n_base + ecs * 16;
    float4 w0 = *(const float4*)(bias + col);
    float4 w1 = *(const float4*)(bias + col + 4);
    float4 w2 = *(const float4*)(bias + col + 8);
    float4 w3 = *(const float4*)(bias + col + 12);
    e0.x += w0.x; e0.y += w0.y; e0.z += w0.z; e0.w += w0.w;
    e1.x += w1.x; e1.y += w1.y; e1.z += w1.z; e1.w += w1.w;
    e2.x += w2.x; e2.y += w2.y; e2.z += w2.z; e2.w += w2.w;
    e3.x += w3.x; e3.y += w3.y; e3.z += w3.z; e3.w += w3.w;
    size_t rg = (size_t)(m_base + ebnd * 64 + mt * 16 + erow);
    float* dst = Cout + rg * NOUT + col;
    *(float4*)dst = e0;
    *(float4*)(dst + 4) = e1;
    *(float4*)(dst + 8) = e2;
    *(float4*)(dst + 12) = e3;
    __syncthreads();
  }
}

// ---------------------------------------------------------------------------
extern "C" void kernel_launch(void* const* d_in, const int* in_sizes, int n_in,
                              void* d_out, int out_size, void* d_ws, size_t ws_size,
                              hipStream_t stream) {
  const float* x      = (const float*)d_in[0];   // 16*4096*512
  const float* qkv_w  = (const float*)d_in[1];   // 1536*512
  const float* proj_w = (const float*)d_in[2];   // 512*512
  const float* proj_b = (const float*)d_in[3];   // 512
  float* out = (float*)d_out;

  char* ws = (char*)d_ws;
  _Float16* QKVh = (_Float16*)ws;                          // 65536*1536 fp16 = 201,326,592 B
  _Float16* Outh = (_Float16*)(ws + 201326592);            // 65536*512  fp16 =  67,108,864 B
  _Float16* Wq   = (_Float16*)(ws + 268435456);            // 1536*512   fp16 =   1,572,864 B
  _Float16* Wp   = (_Float16*)(ws + 270008320);            // 512*512    fp16 =     524,288 B

  cvt_f32_f16<<<384, 256, 0, stream>>>(qkv_w, Wq, 1536 * 512);
  cvt_f32_f16<<<128, 256, 0, stream>>>(proj_w, Wp, 512 * 512);
  qkv_gemm<<<6144, 256, 0, stream>>>(x, Wq, QKVh);
  attn_win<<<dim3(8, 1024), 256, 0, stream>>>(QKVh, Outh);
  proj_gemm<<<2048, 256, 0, stream>>>(Outh, Wp, proj_b, out);
}

// Round 3
// 587.428 us; speedup vs baseline: 1.2467x; 1.2467x over previous
//
#include <hip/hip_runtime.h>
#include <cstdint>
#include <cstddef>

typedef _Float16 half8 __attribute__((ext_vector_type(8)));
typedef _Float16 half4 __attribute__((ext_vector_type(4)));
typedef float f32x4 __attribute__((ext_vector_type(4)));

// async global->LDS, 16B per lane; LDS dest must be wave-uniform base + lane*16
#define GLDS16(g, l) __builtin_amdgcn_global_load_lds( \
    (__attribute__((address_space(1))) void*)(g), \
    (__attribute__((address_space(3))) void*)(l), 16, 0, 0)

// ---------------------------------------------------------------------------
// fp32 -> fp16 convert
// ---------------------------------------------------------------------------
__global__ __launch_bounds__(256) void cvt_f32_f16(const float* __restrict__ src,
                                                   _Float16* __restrict__ dst, int n) {
  int i = (blockIdx.x * 256 + threadIdx.x) * 8;
  if (i >= n) return;
  float4 a = *(const float4*)(src + i);
  float4 b = *(const float4*)(src + i + 4);
  half8 h;
  h[0] = (_Float16)a.x; h[1] = (_Float16)a.y; h[2] = (_Float16)a.z; h[3] = (_Float16)a.w;
  h[4] = (_Float16)b.x; h[5] = (_Float16)b.y; h[6] = (_Float16)b.z; h[7] = (_Float16)b.w;
  *(half8*)(dst + i) = h;
}

// ---------------------------------------------------------------------------
// GEMM C[m,n] = sum_k A[m,k]*Bw[n,k] (+bias).  A fp16 MxK, Bw fp16 NxK, K=512.
// 128x128 tile, BK=32, 4 waves 2x2, each wave 4x4 16x16x32 MFMAs.
// LDS tiles are bank-swizzled: 16B chunk (row r, chunk c) lives at slot
// (r>>3)*32 + c*8 + (r&7)  -> fragment ds_read_b128 start banks are distinct
// within every consecutive-8-lane octet (conflict-free).
// ---------------------------------------------------------------------------
template<int NOUT, int NT, bool BIAS>
__global__ __launch_bounds__(256, 3) void gemm_bt(const _Float16* __restrict__ A,
                                                  const _Float16* __restrict__ Bw,
                                                  const float* __restrict__ bias,
                                                  void* __restrict__ Cout) {
  constexpr int K = 512;
  __shared__ union {
    struct { _Float16 As[4096]; _Float16 Bs[4096]; } s;  // swizzled 128x32 tiles
    float E[2][16][132];                                  // epilogue staging
  } u;
  const int id  = blockIdx.x;
  const int xcd = id & 7;                 // XCD cohort: N-tiles of a band share L2
  const int jj  = id >> 3;
  const int by  = (jj / NT) * 8 + xcd;
  const int bx  = jj % NT;
  const int m_base = by * 128, n_base = bx * 128;

  const int t    = threadIdx.x;
  const int lane = t & 63;
  const int wid  = t >> 6;
  const int wm   = wid >> 1, wn = wid & 1;
  const int cl   = lane & 15, q = lane >> 4;

  f32x4 acc[4][4] = {};

  // staging: thread t owns slots t and t+256 of each 512-slot tile
  const int s0 = t, s1 = t + 256;
  const int r0 = ((s0 >> 5) << 3) | (s0 & 7), c0 = (s0 >> 3) & 3;
  const int r1 = ((s1 >> 5) << 3) | (s1 & 7), c1 = (s1 >> 3) & 3;
  const _Float16* a0 = A  + (size_t)(m_base + r0) * K + c0 * 8;
  const _Float16* a1 = A  + (size_t)(m_base + r1) * K + c1 * 8;
  const _Float16* b0 = Bw + (size_t)(n_base + r0) * K + c0 * 8;
  const _Float16* b1 = Bw + (size_t)(n_base + r1) * K + c1 * 8;
  char* adst0 = (char*)u.s.As + s0 * 16;
  char* adst1 = (char*)u.s.As + s1 * 16;
  char* bdst0 = (char*)u.s.Bs + s0 * 16;
  char* bdst1 = (char*)u.s.Bs + s1 * 16;

  // fragment read offset (halves): slot within 16-row band = (cl>>3)*32 + q*8 + (cl&7)
  const int fro8 = (((cl >> 3) << 5) + (q << 3) + (cl & 7)) * 8;

  for (int k0 = 0; k0 < K; k0 += 32) {
    GLDS16(a0 + k0, adst0);
    GLDS16(a1 + k0, adst1);
    GLDS16(b0 + k0, bdst0);
    GLDS16(b1 + k0, bdst1);
    __syncthreads();   // drains vmcnt for global_load_lds
    half8 af[4], bf[4];
#pragma unroll
    for (int i = 0; i < 4; i++) af[i] = *(const half8*)(u.s.As + wm * 2048 + i * 512 + fro8);
#pragma unroll
    for (int i = 0; i < 4; i++) bf[i] = *(const half8*)(u.s.Bs + wn * 2048 + i * 512 + fro8);
#pragma unroll
    for (int mt = 0; mt < 4; mt++)
#pragma unroll
      for (int nt = 0; nt < 4; nt++)
        acc[mt][nt] = __builtin_amdgcn_mfma_f32_16x16x32_f16(af[mt], bf[nt], acc[mt][nt], 0, 0, 0);
    __syncthreads();
  }

  // epilogue: C/D layout (row=q*4+r, col=lane&15) -> LDS -> chunk-strided reads
  const int ebnd = t >> 7, erow = (t >> 3) & 15, ecs = t & 7;
#pragma unroll
  for (int mt = 0; mt < 4; mt++) {
#pragma unroll
    for (int nt = 0; nt < 4; nt++)
#pragma unroll
      for (int r = 0; r < 4; r++)
        u.E[wm][q * 4 + r][wn * 64 + nt * 16 + cl] = acc[mt][nt][r];
    __syncthreads();
    const size_t rg = (size_t)(m_base + ebnd * 64 + mt * 16 + erow);
#pragma unroll
    for (int j = 0; j < 4; j++) {
      const int cc = (ecs + 8 * j) * 4;          // column within the 128-wide tile
      float4 e = *(const float4*)&u.E[ebnd][erow][cc];
      if constexpr (BIAS) {
        const float4 bb = *(const float4*)(bias + n_base + cc);
        e.x += bb.x; e.y += bb.y; e.z += bb.z; e.w += bb.w;
        *(float4*)((float*)Cout + rg * NOUT + n_base + cc) = e;
      } else {
        half4 hv;
        hv[0] = (_Float16)e.x; hv[1] = (_Float16)e.y;
        hv[2] = (_Float16)e.z; hv[3] = (_Float16)e.w;
        *(half4*)((_Float16*)Cout + rg * NOUT + n_base + cc) = hv;
      }
    }
    __syncthreads();
  }
}

// ---------------------------------------------------------------------------
// Windowed attention: one block per (head h, window b). W=64, hd=64.
// QKV rows: token = b*64+w; cols: q=h*64+e, k=512+h*64+e, v=1024+h*64+e.
// Q/K staged swizzled (8-chunk rows): chunk (r,ch) at slot (r>>3)*64+ch*8+(r&7).
// ---------------------------------------------------------------------------
__global__ __launch_bounds__(256, 3) void attn_win(const _Float16* __restrict__ QKV,
                                                   _Float16* __restrict__ Out) {
  __shared__ _Float16 Qs[4096];
  __shared__ _Float16 Ks[4096];
  __shared__ _Float16 Vt[64][72];   // V transposed: Vt[e][j], padded rows
  __shared__ _Float16 Ps[64][72];   // softmax probs
  __shared__ _Float16 Os[64][72];   // output staging
  const int h = blockIdx.x, b = blockIdx.y;
  const int t = threadIdx.x;
  const int lane = t & 63, wid = t >> 6;
  const int cl = lane & 15, q = lane >> 4;

  // ---- stage Q,K (async, swizzled) and V (manual transpose) ----
  {
    const int s0 = t, s1 = t + 256;
    const int r0 = ((s0 >> 6) << 3) | (s0 & 7), ch0 = (s0 >> 3) & 7;
    const int r1 = ((s1 >> 6) << 3) | (s1 & 7), ch1 = (s1 >> 3) & 7;
    const _Float16* g0 = QKV + (size_t)(b * 64 + r0) * 1536 + h * 64 + ch0 * 8;
    const _Float16* g1 = QKV + (size_t)(b * 64 + r1) * 1536 + h * 64 + ch1 * 8;
    GLDS16(g0,       (char*)Qs + s0 * 16);
    GLDS16(g1,       (char*)Qs + s1 * 16);
    GLDS16(g0 + 512, (char*)Ks + s0 * 16);
    GLDS16(g1 + 512, (char*)Ks + s1 * 16);

    const int vj = t & 63, vp = t >> 6;   // row j of V, 16-half chunk vp
    const _Float16* vsrc = QKV + (size_t)(b * 64 + vj) * 1536 + 1024 + h * 64 + vp * 16;
    half8 v0 = *(const half8*)vsrc;
    half8 v1 = *(const half8*)(vsrc + 8);
#pragma unroll
    for (int i = 0; i < 8; i++) Vt[vp * 16 + i][vj] = v0[i];
#pragma unroll
    for (int i = 0; i < 8; i++) Vt[vp * 16 + 8 + i][vj] = v1[i];
  }
  __syncthreads();

  const int m0 = wid * 16;   // wave's 16 query rows
  // swizzled fragment offset (halves), row band + cl, chunk ks*4+q
  const int fq8 = ((((cl >> 3) << 6) + (q << 3) + (cl & 7))) * 8;

  // ---- S = Q K^T ----
  f32x4 s[4] = {};
#pragma unroll
  for (int ks = 0; ks < 2; ks++) {
    half8 a = *(const half8*)(Qs + wid * 1024 + ks * 256 + fq8);
#pragma unroll
    for (int nt = 0; nt < 4; nt++) {
      half8 bb = *(const half8*)(Ks + nt * 1024 + ks * 256 + fq8);
      s[nt] = __builtin_amdgcn_mfma_f32_16x16x32_f16(a, bb, s[nt], 0, 0, 0);
    }
  }

  // ---- softmax over 64 keys per row (row=q*4+r, keys spread over cl x nt) ----
  constexpr float SC = 0.125f * 1.44269504088896340736f;  // scale * log2(e)
#pragma unroll
  for (int r = 0; r < 4; r++) {
    float mx = fmaxf(fmaxf(s[0][r], s[1][r]), fmaxf(s[2][r], s[3][r]));
    mx = fmaxf(mx, __shfl_xor(mx, 1));
    mx = fmaxf(mx, __shfl_xor(mx, 2));
    mx = fmaxf(mx, __shfl_xor(mx, 4));
    mx = fmaxf(mx, __shfl_xor(mx, 8));
    float e[4], ssum = 0.f;
#pragma unroll
    for (int nt = 0; nt < 4; nt++) { e[nt] = exp2f((s[nt][r] - mx) * SC); ssum += e[nt]; }
    ssum += __shfl_xor(ssum, 1);
    ssum += __shfl_xor(ssum, 2);
    ssum += __shfl_xor(ssum, 4);
    ssum += __shfl_xor(ssum, 8);
    float inv = 1.f / ssum;
    const int row = m0 + q * 4 + r;
#pragma unroll
    for (int nt = 0; nt < 4; nt++) Ps[row][nt * 16 + cl] = (_Float16)(e[nt] * inv);
  }
  __syncthreads();

  // ---- O = P V  (a: Ps rows; b: Vt rows = V columns; 72-pad => conflict-free) ----
  f32x4 o[4] = {};
#pragma unroll
  for (int ks = 0; ks < 2; ks++) {
    half8 a = *(const half8*)&Ps[m0 + cl][ks * 32 + q * 8];
#pragma unroll
    for (int nt = 0; nt < 4; nt++) {
      half8 bb = *(const half8*)&Vt[nt * 16 + cl][ks * 32 + q * 8];
      o[nt] = __builtin_amdgcn_mfma_f32_16x16x32_f16(a, bb, o[nt], 0, 0, 0);
    }
  }
#pragma unroll
  for (int nt = 0; nt < 4; nt++)
#pragma unroll
    for (int r = 0; r < 4; r++)
      Os[m0 + q * 4 + r][nt * 16 + cl] = (_Float16)o[nt][r];
  __syncthreads();

  // ---- coalesced write-out ----
  {
    const int row = t >> 2, cs = t & 3;
    half8 h0 = *(const half8*)&Os[row][cs * 16];
    half8 h1 = *(const half8*)&Os[row][cs * 16 + 8];
    _Float16* dst = Out + (size_t)(b * 64 + row) * 512 + h * 64 + cs * 16;
    *(half8*)dst = h0;
    *((half8*)dst + 1) = h1;
  }
}

// ---------------------------------------------------------------------------
extern "C" void kernel_launch(void* const* d_in, const int* in_sizes, int n_in,
                              void* d_out, int out_size, void* d_ws, size_t ws_size,
                              hipStream_t stream) {
  const float* x      = (const float*)d_in[0];   // 16*4096*512
  const float* qkv_w  = (const float*)d_in[1];   // 1536*512
  const float* proj_w = (const float*)d_in[2];   // 512*512
  const float* proj_b = (const float*)d_in[3];   // 512
  float* out = (float*)d_out;

  char* ws = (char*)d_ws;
  _Float16* QKVh = (_Float16*)ws;                 // 65536*1536 fp16 = 201,326,592 B
  _Float16* Xh   = (_Float16*)(ws + 201326592);   // 65536*512 fp16 = 67,108,864 B
  _Float16* Outh = Xh;                            // alias: Xh dead after qkv_gemm
  _Float16* Wq   = (_Float16*)(ws + 268435456);   // 1536*512 fp16
  _Float16* Wp   = (_Float16*)(ws + 270008320);   // 512*512 fp16

  // x: 33,554,432 elems / (256 thr * 8 elem) = 16384 blocks (8192 was the R2 bug)
  cvt_f32_f16<<<16384, 256, 0, stream>>>(x, Xh, 16 * 4096 * 512);
  cvt_f32_f16<<<384, 256, 0, stream>>>(qkv_w, Wq, 1536 * 512);
  cvt_f32_f16<<<128, 256, 0, stream>>>(proj_w, Wp, 512 * 512);
  gemm_bt<1536, 12, false><<<6144, 256, 0, stream>>>(Xh, Wq, nullptr, QKVh);
  attn_win<<<dim3(8, 1024), 256, 0, stream>>>(QKVh, Outh);
  gemm_bt<512, 4, true><<<2048, 256, 0, stream>>>(Outh, Wp, proj_b, out);
}

// Round 4
// 580.563 us; speedup vs baseline: 1.2614x; 1.0118x over previous
//
#include <hip/hip_runtime.h>
#include <cstdint>
#include <cstddef>

typedef _Float16 half8 __attribute__((ext_vector_type(8)));
typedef _Float16 half4 __attribute__((ext_vector_type(4)));
typedef float f32x4 __attribute__((ext_vector_type(4)));

// async global->LDS, 16B per lane; LDS dest must be wave-uniform base + lane*16
#define GLDS16(g, l) __builtin_amdgcn_global_load_lds( \
    (__attribute__((address_space(1))) void*)(g), \
    (__attribute__((address_space(3))) void*)(l), 16, 0, 0)

// ---------------------------------------------------------------------------
// fp32 -> fp16 convert
// ---------------------------------------------------------------------------
__global__ __launch_bounds__(256) void cvt_f32_f16(const float* __restrict__ src,
                                                   _Float16* __restrict__ dst, int n) {
  int i = (blockIdx.x * 256 + threadIdx.x) * 8;
  if (i >= n) return;
  float4 a = *(const float4*)(src + i);
  float4 b = *(const float4*)(src + i + 4);
  half8 h;
  h[0] = (_Float16)a.x; h[1] = (_Float16)a.y; h[2] = (_Float16)a.z; h[3] = (_Float16)a.w;
  h[4] = (_Float16)b.x; h[5] = (_Float16)b.y; h[6] = (_Float16)b.z; h[7] = (_Float16)b.w;
  *(half8*)(dst + i) = h;
}

// ---------------------------------------------------------------------------
// GEMM C[m,n] = sum_k A[m,k]*Bw[n,k] (+bias).  A fp16 MxK, Bw fp16 NxK, K=512.
// 128x128 tile, BK=32, 4 waves 2x2, each wave 4x4 16x16x32 MFMAs.
// LDS tiles stored in MFMA FRAGMENT ORDER: within each 16-row band, 16B chunk
// (row r, k-chunk c) lives at slot c*16 + r.  Every fragment ds_read_b128 is
// then band_base + lane*16 (bank group == lane&7) -> conflict-free at any
// LDS scheduling granularity (identical pattern to global_load_lds writes).
// ---------------------------------------------------------------------------
template<int NOUT, int NT, bool BIAS>
__global__ __launch_bounds__(256, 3) void gemm_bt(const _Float16* __restrict__ A,
                                                  const _Float16* __restrict__ Bw,
                                                  const float* __restrict__ bias,
                                                  void* __restrict__ Cout) {
  constexpr int K = 512;
  __shared__ union {
    struct { _Float16 As[4096]; _Float16 Bs[4096]; } s;  // fragment-order 128x32 tiles
    float E[2][16][132];                                  // epilogue staging
  } u;
  const int id  = blockIdx.x;
  const int xcd = id & 7;                 // XCD cohort: N-tiles of a band share L2
  const int jj  = id >> 3;
  const int by  = (jj / NT) * 8 + xcd;
  const int bx  = jj % NT;
  const int m_base = by * 128, n_base = bx * 128;

  const int t    = threadIdx.x;
  const int lane = t & 63;
  const int wid  = t >> 6;
  const int wm   = wid >> 1, wn = wid & 1;
  const int cl   = lane & 15, q = lane >> 4;

  f32x4 acc[4][4] = {};

  // staging: thread t owns slots t and t+256.
  // slot s -> band = s>>6 (16 rows), k-chunk c = (s>>4)&3, row r = s&15
  const int s0 = t, s1 = t + 256;
  const int r0 = ((s0 >> 6) << 4) | (s0 & 15), c0 = (s0 >> 4) & 3;
  const int r1 = ((s1 >> 6) << 4) | (s1 & 15), c1 = (s1 >> 4) & 3;
  const _Float16* a0 = A  + (size_t)(m_base + r0) * K + c0 * 8;
  const _Float16* a1 = A  + (size_t)(m_base + r1) * K + c1 * 8;
  const _Float16* b0 = Bw + (size_t)(n_base + r0) * K + c0 * 8;
  const _Float16* b1 = Bw + (size_t)(n_base + r1) * K + c1 * 8;
  char* adst0 = (char*)u.s.As + s0 * 16;
  char* adst1 = (char*)u.s.As + s1 * 16;
  char* bdst0 = (char*)u.s.Bs + s0 * 16;
  char* bdst1 = (char*)u.s.Bs + s1 * 16;

  const int lane8 = lane * 8;   // fragment offset in halves within a band

  for (int k0 = 0; k0 < K; k0 += 32) {
    GLDS16(a0 + k0, adst0);
    GLDS16(a1 + k0, adst1);
    GLDS16(b0 + k0, bdst0);
    GLDS16(b1 + k0, bdst1);
    __syncthreads();   // drains vmcnt for global_load_lds
    half8 af[4], bf[4];
#pragma unroll
    for (int i = 0; i < 4; i++) af[i] = *(const half8*)(u.s.As + (wm * 4 + i) * 512 + lane8);
#pragma unroll
    for (int i = 0; i < 4; i++) bf[i] = *(const half8*)(u.s.Bs + (wn * 4 + i) * 512 + lane8);
#pragma unroll
    for (int mt = 0; mt < 4; mt++)
#pragma unroll
      for (int nt = 0; nt < 4; nt++)
        acc[mt][nt] = __builtin_amdgcn_mfma_f32_16x16x32_f16(af[mt], bf[nt], acc[mt][nt], 0, 0, 0);
    __syncthreads();
  }

  // epilogue: C/D layout (row=q*4+r, col=lane&15) -> LDS -> group-aligned reads
  const int ebnd = t >> 7, erow = (t >> 3) & 15, ecs = t & 7;
#pragma unroll
  for (int mt = 0; mt < 4; mt++) {
#pragma unroll
    for (int nt = 0; nt < 4; nt++)
#pragma unroll
      for (int r = 0; r < 4; r++)
        u.E[wm][q * 4 + r][wn * 64 + nt * 16 + cl] = acc[mt][nt][r];
    __syncthreads();
    const size_t rg = (size_t)(m_base + ebnd * 64 + mt * 16 + erow);
#pragma unroll
    for (int j = 0; j < 4; j++) {
      // E row stride = 132 floats = 33 chunks -> bank group = (erow + chunk) & 7.
      // chunk = ((ecs - erow) & 7) + 8j  =>  group = ecs = lane&7 (conflict-free)
      const int ch = ((ecs - erow) & 7) + 8 * j;
      const int cc = ch * 4;
      float4 e = *(const float4*)&u.E[ebnd][erow][cc];
      if constexpr (BIAS) {
        const float4 bb = *(const float4*)(bias + n_base + cc);
        e.x += bb.x; e.y += bb.y; e.z += bb.z; e.w += bb.w;
        *(float4*)((float*)Cout + rg * NOUT + n_base + cc) = e;
      } else {
        half4 hv;
        hv[0] = (_Float16)e.x; hv[1] = (_Float16)e.y;
        hv[2] = (_Float16)e.z; hv[3] = (_Float16)e.w;
        *(half4*)((_Float16*)Cout + rg * NOUT + n_base + cc) = hv;
      }
    }
    __syncthreads();
  }
}

// ---------------------------------------------------------------------------
// Windowed attention: one block per (head h, window b). W=64, hd=64.
// QKV rows: token = b*64+w; cols: q=h*64+e, k=512+h*64+e, v=1024+h*64+e.
// Q/K staged in fragment order: band (16 rows) x 8 chunks; chunk (r,c) of a
// band at slot c*16 + r  ->  fragment reads are band_base + lane*16.
// ---------------------------------------------------------------------------
__global__ __launch_bounds__(256, 3) void attn_win(const _Float16* __restrict__ QKV,
                                                   _Float16* __restrict__ Out) {
  __shared__ _Float16 Qs[4096];
  __shared__ _Float16 Ks[4096];
  __shared__ _Float16 Vt[64][72];   // V transposed: Vt[e][j], padded rows
  __shared__ _Float16 Ps[64][72];   // softmax probs
  __shared__ _Float16 Os[64][72];   // output staging
  const int h = blockIdx.x, b = blockIdx.y;
  const int t = threadIdx.x;
  const int lane = t & 63, wid = t >> 6;
  const int cl = lane & 15, q = lane >> 4;

  // ---- stage Q,K (async, fragment order) and V (manual transpose) ----
  {
    // slot s -> band = s>>7 (16 rows), chunk c = (s>>4)&7, row r = s&15
    const int s0 = t, s1 = t + 256;
    const int r0 = ((s0 >> 7) << 4) | (s0 & 15), ch0 = (s0 >> 4) & 7;
    const int r1 = ((s1 >> 7) << 4) | (s1 & 15), ch1 = (s1 >> 4) & 7;
    const _Float16* g0 = QKV + (size_t)(b * 64 + r0) * 1536 + h * 64 + ch0 * 8;
    const _Float16* g1 = QKV + (size_t)(b * 64 + r1) * 1536 + h * 64 + ch1 * 8;
    GLDS16(g0,       (char*)Qs + s0 * 16);
    GLDS16(g1,       (char*)Qs + s1 * 16);
    GLDS16(g0 + 512, (char*)Ks + s0 * 16);
    GLDS16(g1 + 512, (char*)Ks + s1 * 16);

    const int vj = t & 63, vp = t >> 6;   // row j of V, 16-half chunk vp
    const _Float16* vsrc = QKV + (size_t)(b * 64 + vj) * 1536 + 1024 + h * 64 + vp * 16;
    half8 v0 = *(const half8*)vsrc;
    half8 v1 = *(const half8*)(vsrc + 8);
#pragma unroll
    for (int i = 0; i < 8; i++) Vt[vp * 16 + i][vj] = v0[i];
#pragma unroll
    for (int i = 0; i < 8; i++) Vt[vp * 16 + 8 + i][vj] = v1[i];
  }
  __syncthreads();

  const int m0 = wid * 16;      // wave's 16 query rows
  const int lane8 = lane * 8;   // fragment offset in halves within a band

  // ---- S = Q K^T ----
  f32x4 s[4] = {};
#pragma unroll
  for (int ks = 0; ks < 2; ks++) {
    half8 a = *(const half8*)(Qs + wid * 1024 + ks * 512 + lane8);
#pragma unroll
    for (int nt = 0; nt < 4; nt++) {
      half8 bb = *(const half8*)(Ks + nt * 1024 + ks * 512 + lane8);
      s[nt] = __builtin_amdgcn_mfma_f32_16x16x32_f16(a, bb, s[nt], 0, 0, 0);
    }
  }

  // ---- softmax over 64 keys per row (row=q*4+r, keys spread over cl x nt) ----
  constexpr float SC = 0.125f * 1.44269504088896340736f;  // scale * log2(e)
#pragma unroll
  for (int r = 0; r < 4; r++) {
    float mx = fmaxf(fmaxf(s[0][r], s[1][r]), fmaxf(s[2][r], s[3][r]));
    mx = fmaxf(mx, __shfl_xor(mx, 1));
    mx = fmaxf(mx, __shfl_xor(mx, 2));
    mx = fmaxf(mx, __shfl_xor(mx, 4));
    mx = fmaxf(mx, __shfl_xor(mx, 8));
    float e[4], ssum = 0.f;
#pragma unroll
    for (int nt = 0; nt < 4; nt++) { e[nt] = exp2f((s[nt][r] - mx) * SC); ssum += e[nt]; }
    ssum += __shfl_xor(ssum, 1);
    ssum += __shfl_xor(ssum, 2);
    ssum += __shfl_xor(ssum, 4);
    ssum += __shfl_xor(ssum, 8);
    float inv = 1.f / ssum;
    const int row = m0 + q * 4 + r;
#pragma unroll
    for (int nt = 0; nt < 4; nt++) Ps[row][nt * 16 + cl] = (_Float16)(e[nt] * inv);
  }
  __syncthreads();

  // ---- O = P V  (a: Ps rows; b: Vt rows = V columns; 72-pad rotates groups) ----
  f32x4 o[4] = {};
#pragma unroll
  for (int ks = 0; ks < 2; ks++) {
    half8 a = *(const half8*)&Ps[m0 + cl][ks * 32 + q * 8];
#pragma unroll
    for (int nt = 0; nt < 4; nt++) {
      half8 bb = *(const half8*)&Vt[nt * 16 + cl][ks * 32 + q * 8];
      o[nt] = __builtin_amdgcn_mfma_f32_16x16x32_f16(a, bb, o[nt], 0, 0, 0);
    }
  }
#pragma unroll
  for (int nt = 0; nt < 4; nt++)
#pragma unroll
    for (int r = 0; r < 4; r++)
      Os[m0 + q * 4 + r][nt * 16 + cl] = (_Float16)o[nt][r];
  __syncthreads();

  // ---- coalesced write-out ----
  {
    const int row = t >> 2, cs = t & 3;
    half8 h0 = *(const half8*)&Os[row][cs * 16];
    half8 h1 = *(const half8*)&Os[row][cs * 16 + 8];
    _Float16* dst = Out + (size_t)(b * 64 + row) * 512 + h * 64 + cs * 16;
    *(half8*)dst = h0;
    *((half8*)dst + 1) = h1;
  }
}

// ---------------------------------------------------------------------------
extern "C" void kernel_launch(void* const* d_in, const int* in_sizes, int n_in,
                              void* d_out, int out_size, void* d_ws, size_t ws_size,
                              hipStream_t stream) {
  const float* x      = (const float*)d_in[0];   // 16*4096*512
  const float* qkv_w  = (const float*)d_in[1];   // 1536*512
  const float* proj_w = (const float*)d_in[2];   // 512*512
  const float* proj_b = (const float*)d_in[3];   // 512
  float* out = (float*)d_out;

  char* ws = (char*)d_ws;
  _Float16* QKVh = (_Float16*)ws;                 // 65536*1536 fp16 = 201,326,592 B
  _Float16* Xh   = (_Float16*)(ws + 201326592);   // 65536*512 fp16 = 67,108,864 B
  _Float16* Outh = Xh;                            // alias: Xh dead after qkv_gemm
  _Float16* Wq   = (_Float16*)(ws + 268435456);   // 1536*512 fp16
  _Float16* Wp   = (_Float16*)(ws + 270008320);   // 512*512 fp16

  cvt_f32_f16<<<16384, 256, 0, stream>>>(x, Xh, 16 * 4096 * 512);
  cvt_f32_f16<<<384, 256, 0, stream>>>(qkv_w, Wq, 1536 * 512);
  cvt_f32_f16<<<128, 256, 0, stream>>>(proj_w, Wp, 512 * 512);
  gemm_bt<1536, 12, false><<<6144, 256, 0, stream>>>(Xh, Wq, nullptr, QKVh);
  attn_win<<<dim3(8, 1024), 256, 0, stream>>>(QKVh, Outh);
  gemm_bt<512, 4, true><<<2048, 256, 0, stream>>>(Outh, Wp, proj_b, out);
}